// Round 2
// baseline (179.918 us; speedup 1.0000x reference)
//
#include <hip/hip_runtime.h>
#include <utility>

#define T_SEQ 256
#define NF 8
#define HID 16
#define NBATCH 4096

// ds_swizzle with compile-time BitMode pattern: src = ((lane & and) | or) ^ xor
template<int PAT>
__device__ __forceinline__ float dswz(float v) {
  return __int_as_float(__builtin_amdgcn_ds_swizzle(__float_as_int(v), PAT));
}

__device__ __forceinline__ float fsigm(float x) {
  // 1 / (1 + 2^(-x*log2e))
  float e = __builtin_amdgcn_exp2f(-1.4426950408889634f * x);
  return __builtin_amdgcn_rcpf(1.0f + e);
}
__device__ __forceinline__ float ftanh_(float x) {
  // 1 - 2 / (2^(2x*log2e) + 1)
  float e = __builtin_amdgcn_exp2f(2.8853900817779268f * x);
  return 1.0f - 2.0f * __builtin_amdgcn_rcpf(e + 1.0f);
}

// dst[k] = v taken from lane ((lane & 0x10) | k) : broadcast within 16-lane group
template<int... Ks>
__device__ __forceinline__ void bcast16(float (&dst)[16], float v, std::integer_sequence<int, Ks...>) {
  ((dst[Ks] = dswz<((Ks) << 5) | 0x10>(v)), ...);
}
template<int... Ks>
__device__ __forceinline__ void bcast8(float (&dst)[8], float v, std::integer_sequence<int, Ks...>) {
  ((dst[Ks] = dswz<((Ks) << 5) | 0x10>(v)), ...);
}

template<int S>
__device__ __forceinline__ void enc_step(const float (&xr)[8], float (&h)[16], float& c,
    const float (&wih)[4][8], const float (&whh)[4][16], const float (&bias)[4]) {
  float a0 = bias[0], a1 = bias[1], a2 = bias[2], a3 = bias[3];
#pragma unroll
  for (int k = 0; k < 8; ++k) {
    // broadcast x_t[k] from lane S of the 16-lane group (same pattern for all k)
    float xt = dswz<((S) << 5) | 0x10>(xr[k]);
    a0 = fmaf(wih[0][k], xt, a0);
    a1 = fmaf(wih[1][k], xt, a1);
    a2 = fmaf(wih[2][k], xt, a2);
    a3 = fmaf(wih[3][k], xt, a3);
  }
#pragma unroll
  for (int k = 0; k < 16; ++k) {
    a0 = fmaf(whh[0][k], h[k], a0);
    a1 = fmaf(whh[1][k], h[k], a1);
    a2 = fmaf(whh[2][k], h[k], a2);
    a3 = fmaf(whh[3][k], h[k], a3);
  }
  float iv = fsigm(a0);
  float fv = fsigm(a1);
  float gv = ftanh_(a2);
  float ov = fsigm(a3);
  c = fmaf(fv, c, iv * gv);
  float hj = ov * ftanh_(c);
  bcast16(h, hj, std::make_integer_sequence<int, 16>{});
}

template<int... Ss>
__device__ __forceinline__ void enc_chunk(const float (&xr)[8], float (&h)[16], float& c,
    const float (&wih)[4][8], const float (&whh)[4][16], const float (&bias)[4],
    std::integer_sequence<int, Ss...>) {
  ((enc_step<Ss>(xr, h, c, wih, whh, bias)), ...);
}

__global__ __launch_bounds__(256, 1)
void lstm_ae_kernel(const float* __restrict__ x,
                    const float* __restrict__ eWih, const float* __restrict__ eWhh,
                    const float* __restrict__ ebih, const float* __restrict__ ebhh,
                    const float* __restrict__ dWih, const float* __restrict__ dWhh,
                    const float* __restrict__ dbih, const float* __restrict__ dbhh,
                    const float* __restrict__ oW, const float* __restrict__ obv,
                    float* __restrict__ out) {
  const int tid = threadIdx.x;
  const int j = tid & 15;          // hidden unit (encoder) / gate slot (decoder)
  const int u = j & 7;             // decoder unit / output row
  const int elem = blockIdx.x * 16 + (tid >> 4);  // 16 batch elems per block
  const float* xb = x + (size_t)elem * (T_SEQ * NF);

  // ---- encoder weights: lane j owns gate rows {j, 16+j, 32+j, 48+j} (i,f,g,o) ----
  float wih[4][8], whh[4][16], bias[4];
#pragma unroll
  for (int g = 0; g < 4; ++g) {
    const int row = g * 16 + j;
#pragma unroll
    for (int k = 0; k < 8; ++k) wih[g][k] = eWih[row * 8 + k];
#pragma unroll
    for (int k = 0; k < 16; ++k) whh[g][k] = eWhh[row * 16 + k];
    bias[g] = ebih[row] + ebhh[row];
  }

  float h[16];
#pragma unroll
  for (int k = 0; k < 16; ++k) h[k] = 0.0f;
  float c = 0.0f;

  // ---- encoder: 16 chunks of 16 timesteps; lane j holds x[t0+j][0..8) (coalesced 512B/group) ----
  {
    const float4* xp = reinterpret_cast<const float4*>(xb + j * NF);
    float4 va = xp[0];
    float4 vb = xp[1];
    for (int chunk = 0; chunk < T_SEQ / 16; ++chunk) {
      float xr[8] = {va.x, va.y, va.z, va.w, vb.x, vb.y, vb.z, vb.w};
      if (chunk + 1 < T_SEQ / 16) {  // prefetch next chunk before compute
        const float4* xn = reinterpret_cast<const float4*>(xb + ((chunk + 1) * 16 + j) * NF);
        va = xn[0];
        vb = xn[1];
      }
      enc_chunk(xr, h, c, wih, whh, bias, std::make_integer_sequence<int, 16>{});
    }
  }
  // h[0..15] now = final encoder hidden state (replicated on all lanes of the group)

  // ---- decoder weights: lane j owns gate rows {j, j+16} of 32 ----
  float dwih[2][16], dwhh[2][8], dbias[2];
#pragma unroll
  for (int p = 0; p < 2; ++p) {
    const int row = p * 16 + j;
#pragma unroll
    for (int k = 0; k < 16; ++k) dwih[p][k] = dWih[row * 16 + k];
#pragma unroll
    for (int k = 0; k < 8; ++k) dwhh[p][k] = dWhh[row * 8 + k];
    dbias[p] = dbih[row] + dbhh[row];
  }
  float ow[8];
#pragma unroll
  for (int k = 0; k < 8; ++k) ow[k] = oW[u * 8 + k];
  const float outb = obv[u];

  // decoder input is constant (repeated h_enc): precompute gate constants once
  float ca = dbias[0], cb = dbias[1];
#pragma unroll
  for (int k = 0; k < 16; ++k) {
    ca = fmaf(dwih[0][k], h[k], ca);
    cb = fmaf(dwih[1][k], h[k], cb);
  }

  float hd[8];
#pragma unroll
  for (int k = 0; k < 8; ++k) hd[k] = 0.0f;
  float cd = 0.0f;
  const bool hi = (j >= 8);
  float* outp = out + (size_t)elem * (T_SEQ * NF) + u;

  for (int t = 0; t < T_SEQ; ++t) {
    float a0 = ca, a1 = cb;
#pragma unroll
    for (int k = 0; k < 8; ++k) {
      a0 = fmaf(dwhh[0][k], hd[k], a0);
      a1 = fmaf(dwhh[1][k], hd[k], a1);
    }
    // lanes j<8 hold (i,g) of unit u; lanes j>=8 hold (f,o). Exchange with lane j^8.
    const float b0 = dswz<(8 << 10) | 0x1F>(a0);
    const float b1 = dswz<(8 << 10) | 0x1F>(a1);
    const float ipre = hi ? b0 : a0;
    const float fpre = hi ? a0 : b0;
    const float gpre = hi ? b1 : a1;
    const float opre = hi ? a1 : b1;
    const float iv = fsigm(ipre);
    const float fv = fsigm(fpre);
    const float gv = ftanh_(gpre);
    const float ov = fsigm(opre);
    cd = fmaf(fv, cd, iv * gv);
    const float hu = ov * ftanh_(cd);  // both halves compute identical h[u]
    bcast8(hd, hu, std::make_integer_sequence<int, 8>{});
    // fused output projection: y[u] = out_b[u] + sum_k out_W[u][k] * hd[k]
    float y = outb;
#pragma unroll
    for (int k = 0; k < 8; ++k) y = fmaf(ow[k], hd[k], y);
    if (!hi) outp[(size_t)t * NF] = y;
  }
}

extern "C" void kernel_launch(void* const* d_in, const int* in_sizes, int n_in,
                              void* d_out, int out_size, void* d_ws, size_t ws_size,
                              hipStream_t stream) {
  const float* x    = (const float*)d_in[0];
  const float* eWih = (const float*)d_in[1];
  const float* eWhh = (const float*)d_in[2];
  const float* ebih = (const float*)d_in[3];
  const float* ebhh = (const float*)d_in[4];
  const float* dWih = (const float*)d_in[5];
  const float* dWhh = (const float*)d_in[6];
  const float* dbih = (const float*)d_in[7];
  const float* dbhh = (const float*)d_in[8];
  const float* oW   = (const float*)d_in[9];
  const float* obv  = (const float*)d_in[10];
  float* out = (float*)d_out;

  dim3 grid(NBATCH / 16);   // 256 blocks -> 1 per CU
  dim3 block(256);          // 4 waves; each 16-lane group = one batch element
  hipLaunchKernelGGL(lstm_ae_kernel, grid, block, 0, stream,
                     x, eWih, eWhh, ebih, ebhh, dWih, dWhh, dbih, dbhh, oW, obv, out);
}

// Round 3
// 165.273 us; speedup vs baseline: 1.0886x; 1.0886x over previous
//
#include <hip/hip_runtime.h>

typedef float f2 __attribute__((ext_vector_type(2)));

#define T_SEQ 256
#define NF 8
#define HID 16
#define NBATCH 4096

// ds_swizzle BitMode: offset = (xor<<10) | (or<<5) | and ; src=((lane&and)|or)^xor within 32-lane groups
template<int PAT>
__device__ __forceinline__ float dswz(float v) {
  return __int_as_float(__builtin_amdgcn_ds_swizzle(__float_as_int(v), PAT));
}

__device__ __forceinline__ float fsigm(float x) {
  float e = __builtin_amdgcn_exp2f(-1.4426950408889634f * x);
  return __builtin_amdgcn_rcpf(1.0f + e);
}
__device__ __forceinline__ float ftanh_(float x) {
  float e = __builtin_amdgcn_exp2f(2.8853900817779268f * x);
  return 1.0f - 2.0f * __builtin_amdgcn_rcpf(e + 1.0f);
}

__device__ __forceinline__ f2 pkfma(f2 a, f2 b, f2 c) {
#if __has_builtin(__builtin_elementwise_fma)
  return __builtin_elementwise_fma(a, b, c);   // -> v_pk_fma_f32 on gfx950
#else
  return a * b + c;
#endif
}

// per-group LDS: [0..32) h/hd slots, [32..160) x double-buffer, pad to 168 (bank shift 8 between groups)
#define GSTRIDE 168

__global__ __launch_bounds__(256, 2)
void lstm_ae_kernel(const float* __restrict__ x,
                    const float* __restrict__ eWih, const float* __restrict__ eWhh,
                    const float* __restrict__ ebih, const float* __restrict__ ebhh,
                    const float* __restrict__ dWih, const float* __restrict__ dWhh,
                    const float* __restrict__ dbih, const float* __restrict__ dbhh,
                    const float* __restrict__ oW, const float* __restrict__ obv,
                    float* __restrict__ out) {
  const int tid = threadIdx.x;
  const int l = tid & 31;            // lane within 32-lane group (= one batch element)
  const int grp = tid >> 5;          // group within block (0..7)
  const int elem = blockIdx.x * 8 + grp;

  __shared__ float smem[8 * GSTRIDE];
  float* const sm = smem + grp * GSTRIDE;
  float* const smh = sm;             // 32 slots; h in [0..16)
  float* const smx = sm + 32;        // 2 x 64 floats (8 timesteps x 8 feats, double-buffered)

  // ---- encoder weights: lane l owns gate rows l (i/f) and l+32 (g/o) ----
  f2 wih[2][4], whh[2][8];
  float eb[2];
#pragma unroll
  for (int p = 0; p < 2; ++p) {
    const int row = l + p * 32;
    const f2* wp = (const f2*)(eWih + row * 8);
#pragma unroll
    for (int k = 0; k < 4; ++k) wih[p][k] = wp[k];
    const f2* wq = (const f2*)(eWhh + row * 16);
#pragma unroll
    for (int k = 0; k < 8; ++k) whh[p][k] = wq[k];
    eb[p] = ebih[row] + ebhh[row];
  }

  const float* xb = x + (size_t)elem * (T_SEQ * NF);
  const bool lo = (l < 16);
  float c = 0.0f;

  smh[l] = 0.0f;                       // h0 = 0 (slots 16..31 are dummies)
  // stage x chunk 0 (8 timesteps = 64 floats; lane l holds float2 at 2l)
  f2 xv = ((const f2*)xb)[l];
  ((f2*)smx)[l] = xv;

  for (int chunk = 0; chunk < T_SEQ / 8; ++chunk) {
    const int cur = chunk & 1;
    f2 xn;
    if (chunk < T_SEQ / 8 - 1) xn = ((const f2*)(xb + (chunk + 1) * 64))[l];  // prefetch
#pragma unroll
    for (int s = 0; s < 8; ++s) {
      // h[0..16) and x_t[0..8) broadcast-read from LDS (same addr across group = free)
      const float4 h4a = ((const float4*)smh)[0];
      const float4 h4b = ((const float4*)smh)[1];
      const float4 h4c = ((const float4*)smh)[2];
      const float4 h4d = ((const float4*)smh)[3];
      const float4 x4a = ((const float4*)(smx + cur * 64 + s * 8))[0];
      const float4 x4b = ((const float4*)(smx + cur * 64 + s * 8))[1];
      const f2 hk[8] = { {h4a.x,h4a.y},{h4a.z,h4a.w},{h4b.x,h4b.y},{h4b.z,h4b.w},
                         {h4c.x,h4c.y},{h4c.z,h4c.w},{h4d.x,h4d.y},{h4d.z,h4d.w} };
      const f2 xk[4] = { {x4a.x,x4a.y},{x4a.z,x4a.w},{x4b.x,x4b.y},{x4b.z,x4b.w} };
      f2 acc0 = {eb[0], 0.0f};
      f2 acc1 = {eb[1], 0.0f};
#pragma unroll
      for (int k = 0; k < 4; ++k) {
        acc0 = pkfma(wih[0][k], xk[k], acc0);
        acc1 = pkfma(wih[1][k], xk[k], acc1);
      }
#pragma unroll
      for (int k = 0; k < 8; ++k) {
        acc0 = pkfma(whh[0][k], hk[k], acc0);
        acc1 = pkfma(whh[1][k], hk[k], acc1);
      }
      const float a0 = acc0.x + acc0.y;   // lo: i_u ; hi: f_u   (u = l&15)
      const float a1 = acc1.x + acc1.y;   // lo: g_u ; hi: o_u
      const float b0 = dswz<0x401F>(a0);  // xor 16: partner's a0
      const float b1 = dswz<0x401F>(a1);
      const float ipre = lo ? a0 : b0;
      const float fpre = lo ? b0 : a0;
      const float gpre = lo ? a1 : b1;
      const float opre = lo ? b1 : a1;
      const float iv = fsigm(ipre);
      const float fv = fsigm(fpre);
      const float gv = ftanh_(gpre);
      const float ov = fsigm(opre);
      c = fmaf(fv, c, iv * gv);
      const float h = ov * ftanh_(c);
      smh[l] = h;                       // publish (lanes l,l^16 write identical value pairs to distinct slots)
    }
    if (chunk < T_SEQ / 8 - 1) ((f2*)(smx + (cur ^ 1) * 64))[l] = xn;
  }
  // smh[0..16) = h_enc

  // ---- decoder: lane l owns gate row l of 32 (i:0-7 f:8-15 g:16-23 o:24-31), unit u = l&7 ----
  float cg;
  f2 dwhh2[4];
  {
    const float4 h4a = ((const float4*)smh)[0];
    const float4 h4b = ((const float4*)smh)[1];
    const float4 h4c = ((const float4*)smh)[2];
    const float4 h4d = ((const float4*)smh)[3];
    const f2 he[8] = { {h4a.x,h4a.y},{h4a.z,h4a.w},{h4b.x,h4b.y},{h4b.z,h4b.w},
                       {h4c.x,h4c.y},{h4c.z,h4c.w},{h4d.x,h4d.y},{h4d.z,h4d.w} };
    f2 acc = {dbih[l] + dbhh[l], 0.0f};
    const f2* wp = (const f2*)(dWih + l * 16);
#pragma unroll
    for (int k = 0; k < 8; ++k) acc = pkfma(wp[k], he[k], acc);
    cg = acc.x + acc.y;                 // constant input+bias contribution (decoder input is h_enc every step)
    const f2* wq = (const f2*)(dWhh + l * 8);
#pragma unroll
    for (int k = 0; k < 4; ++k) dwhh2[k] = wq[k];
  }
  const int u = l & 7;
  f2 ow2[4];
  {
    const f2* op = (const f2*)(oW + u * 8);
#pragma unroll
    for (int k = 0; k < 4; ++k) ow2[k] = op[k];
  }
  const float ob = obv[u];
  const bool b8 = (l & 8) != 0;
  const bool b16 = (l & 16) != 0;
  float cd = 0.0f;
  smh[l] = 0.0f;                        // hd_{-1} = 0 (after h_enc consumed; DS ops in-order within wave)
  float* const outp = out + (size_t)elem * (T_SEQ * NF) + u;

  for (int t = 0; t < T_SEQ; ++t) {
    // hd = h_{t-1}
    const float4 d4a = ((const float4*)smh)[0];
    const float4 d4b = ((const float4*)smh)[1];
    const f2 hd[4] = { {d4a.x,d4a.y},{d4a.z,d4a.w},{d4b.x,d4b.y},{d4b.z,d4b.w} };
    if (t > 0) {
      // lagged output projection: y_{t-1} = out_b[u] + out_W[u,:] . h_{t-1}
      f2 ya = {ob, 0.0f};
#pragma unroll
      for (int k = 0; k < 4; ++k) ya = pkfma(ow2[k], hd[k], ya);
      if (l < 8) outp[(size_t)(t - 1) * NF] = ya.x + ya.y;
    }
    f2 acc = {cg, 0.0f};
#pragma unroll
    for (int k = 0; k < 4; ++k) acc = pkfma(dwhh2[k], hd[k], acc);
    const float a = acc.x + acc.y;
    // butterfly: gather all 4 preactivations of unit u
    const float p1  = dswz<0x201F>(a);   // xor 8
    const float p2a = dswz<0x401F>(a);   // xor 16
    const float p2b = dswz<0x401F>(p1);  // xor 16 of p1 (= row l^24)
    const float s0 = b8 ? p1  : a;
    const float s1 = b8 ? a   : p1;
    const float s2 = b8 ? p2b : p2a;
    const float s3 = b8 ? p2a : p2b;
    const float ipre = b16 ? s2 : s0;
    const float fpre = b16 ? s3 : s1;
    const float gpre = b16 ? s0 : s2;
    const float opre = b16 ? s1 : s3;
    const float iv = fsigm(ipre);
    const float fv = fsigm(fpre);
    const float gv = ftanh_(gpre);
    const float ov = fsigm(opre);
    cd = fmaf(fv, cd, iv * gv);
    const float h = ov * ftanh_(cd);
    smh[l] = h;                          // slots 0..7 valid (all 4 quadrant copies identical)
  }
  // final output y_{255}
  {
    const float4 d4a = ((const float4*)smh)[0];
    const float4 d4b = ((const float4*)smh)[1];
    const f2 hd[4] = { {d4a.x,d4a.y},{d4a.z,d4a.w},{d4b.x,d4b.y},{d4b.z,d4b.w} };
    f2 ya = {ob, 0.0f};
#pragma unroll
    for (int k = 0; k < 4; ++k) ya = pkfma(ow2[k], hd[k], ya);
    if (l < 8) outp[(size_t)(T_SEQ - 1) * NF] = ya.x + ya.y;
  }
}

extern "C" void kernel_launch(void* const* d_in, const int* in_sizes, int n_in,
                              void* d_out, int out_size, void* d_ws, size_t ws_size,
                              hipStream_t stream) {
  const float* x    = (const float*)d_in[0];
  const float* eWih = (const float*)d_in[1];
  const float* eWhh = (const float*)d_in[2];
  const float* ebih = (const float*)d_in[3];
  const float* ebhh = (const float*)d_in[4];
  const float* dWih = (const float*)d_in[5];
  const float* dWhh = (const float*)d_in[6];
  const float* dbih = (const float*)d_in[7];
  const float* dbhh = (const float*)d_in[8];
  const float* oW   = (const float*)d_in[9];
  const float* obv  = (const float*)d_in[10];
  float* out = (float*)d_out;

  dim3 grid(NBATCH / 8);    // 512 blocks -> 2 per CU -> 8 waves/CU (2/SIMD)
  dim3 block(256);          // 4 waves; each 32-lane group = one batch element
  hipLaunchKernelGGL(lstm_ae_kernel, grid, block, 0, stream,
                     x, eWih, eWhh, ebih, ebhh, dWih, dWhh, dbih, dbhh, oW, obv, out);
}